// Round 1
// baseline (1538.208 us; speedup 1.0000x reference)
//
#include <hip/hip_runtime.h>
#include <cstdint>

// ======================= threefry-2x32 (JAX-compatible) =======================
__host__ __device__ inline void tf2x32(uint32_t k0, uint32_t k1,
                                       uint32_t x0, uint32_t x1,
                                       uint32_t& o0, uint32_t& o1) {
  uint32_t ks2 = k0 ^ k1 ^ 0x1BD11BDAu;
  uint32_t v0 = x0 + k0, v1 = x1 + k1;
#define TFR(r) { v0 += v1; v1 = (v1 << r) | (v1 >> (32 - r)); v1 ^= v0; }
  TFR(13) TFR(15) TFR(26) TFR(6)
  v0 += k1;  v1 += ks2 + 1u;
  TFR(17) TFR(29) TFR(16) TFR(24)
  v0 += ks2; v1 += k0 + 2u;
  TFR(13) TFR(15) TFR(26) TFR(6)
  v0 += k0;  v1 += k1 + 3u;
  TFR(17) TFR(29) TFR(16) TFR(24)
  v0 += k1;  v1 += ks2 + 4u;
  TFR(13) TFR(15) TFR(26) TFR(6)
  v0 += ks2; v1 += k0 + 5u;
#undef TFR
  o0 = v0; o1 = v1;
}

// XLA f32 erf_inv (Giles polynomial), matches lax.erf_inv on f32
__device__ inline float erfinv32(float x) {
  float w = -log1pf(-x * x);
  float p;
  if (w < 5.0f) {
    w -= 2.5f;
    p = 2.81022636e-08f;
    p = fmaf(p, w, 3.43273939e-07f);
    p = fmaf(p, w, -3.5233877e-06f);
    p = fmaf(p, w, -4.39150654e-06f);
    p = fmaf(p, w, 0.00021858087f);
    p = fmaf(p, w, -0.00125372503f);
    p = fmaf(p, w, -0.00417768164f);
    p = fmaf(p, w, 0.246640727f);
    p = fmaf(p, w, 1.50140941f);
  } else {
    w = sqrtf(w) - 3.0f;
    p = -0.000200214257f;
    p = fmaf(p, w, 0.000100950558f);
    p = fmaf(p, w, 0.00134934322f);
    p = fmaf(p, w, -0.00367342844f);
    p = fmaf(p, w, 0.00573950773f);
    p = fmaf(p, w, -0.0076224613f);
    p = fmaf(p, w, 0.00943887047f);
    p = fmaf(p, w, 1.00167406f);
    p = fmaf(p, w, 2.83297682f);
  }
  return p * x;
}

// jax.random.normal element idx under partitionable threefry:
// bits = fold(block(key,(0,idx))); uniform in [-0.99999994,1); sqrt(2)*erfinv
__device__ inline float rng_normal(uint32_t k0, uint32_t k1, uint32_t idx) {
  uint32_t o0, o1;
  tf2x32(k0, k1, 0u, idx, o0, o1);
  uint32_t bits = o0 ^ o1;
  float f = __uint_as_float((bits >> 9) | 0x3f800000u) - 1.0f;
  const float lo = -0.999999940395355224609375f;
  float u = fmaxf(lo, f * 2.0f + lo);
  return 1.41421356237f * erfinv32(u);
}

struct RngKeys {
  uint32_t wA0, wA1, bA0, bA1;
  uint32_t wB0, wB1, bB0, bB1;
  uint32_t wC0, wC1, bC0, bC1;
  uint32_t wD0, wD1, bD0, bD1;  // dt
};

// ======================= weight / bias sampling =======================
// Wcat rows [0,1024): W_A + W_dt (summed; E only needs z_A+z_dt)
//          [1024,2048): W_Bp ; [2048,3072): W_C
__global__ __launch_bounds__(256) void gen_weights(
    const float* __restrict__ Awmu, const float* __restrict__ Awlv,
    const float* __restrict__ Dwmu, const float* __restrict__ Dwlv,
    const float* __restrict__ Bwmu, const float* __restrict__ Bwlv,
    const float* __restrict__ Cwmu, const float* __restrict__ Cwlv,
    float* __restrict__ Wcat, RngKeys kk) {
  uint32_t idx = blockIdx.x * 256u + threadIdx.x;  // [0, 3*2^20)
  uint32_t sel = idx >> 20;
  uint32_t e = idx & 0xFFFFFu;
  float w;
  if (sel == 0u) {
    w = Awmu[e] + expf(0.5f * Awlv[e]) * rng_normal(kk.wA0, kk.wA1, e)
      + Dwmu[e] + expf(0.5f * Dwlv[e]) * rng_normal(kk.wD0, kk.wD1, e);
  } else if (sel == 1u) {
    w = Bwmu[e] + expf(0.5f * Bwlv[e]) * rng_normal(kk.wB0, kk.wB1, e);
  } else {
    w = Cwmu[e] + expf(0.5f * Cwlv[e]) * rng_normal(kk.wC0, kk.wC1, e);
  }
  Wcat[idx] = w;
}

__global__ __launch_bounds__(256) void gen_bias(
    const float* __restrict__ Abmu, const float* __restrict__ Ablv,
    const float* __restrict__ Dbmu, const float* __restrict__ Dblv,
    const float* __restrict__ Bbmu, const float* __restrict__ Bblv,
    const float* __restrict__ Cbmu, const float* __restrict__ Cblv,
    float* __restrict__ bcat, RngKeys kk) {
  uint32_t o = blockIdx.x * 256u + threadIdx.x;  // 0..3071
  uint32_t e = o & 1023u;
  float b;
  if (o < 1024u)
    b = Abmu[e] + expf(0.5f * Ablv[e]) * rng_normal(kk.bA0, kk.bA1, e)
      + Dbmu[e] + expf(0.5f * Dblv[e]) * rng_normal(kk.bD0, kk.bD1, e);
  else if (o < 2048u)
    b = Bbmu[e] + expf(0.5f * Bblv[e]) * rng_normal(kk.bB0, kk.bB1, e);
  else
    b = Cbmu[e] + expf(0.5f * Cblv[e]) * rng_normal(kk.bC0, kk.bC1, e);
  bcat[o] = b;
}

// ======================= fp32 GEMM + fused epilogue =======================
// Z[m, 0:1024)    = E  = exp(-exp(z_AD))
// Z[m, 1024:2048) = Bx = z_B * x[m, n-1024]
// Z[m, 2048:3072) = C  = z_C
#define BM 64
#define BN 64
#define BK 16

__global__ __launch_bounds__(256) void gemm_fused(
    const float* __restrict__ X,     // [16384,1024]
    const float* __restrict__ Wcat,  // [3072,1024] row-major (out, in)
    const float* __restrict__ bcat,  // [3072]
    float* __restrict__ Z) {         // [16384,3072]
  __shared__ __align__(16) float As[BK][BM + 4];
  __shared__ __align__(16) float Bs[BK][BN + 4];
  const int t = threadIdx.x;
  const int tx = t & 15, ty = t >> 4;
  const int m0 = blockIdx.y * BM;
  const int n0 = blockIdx.x * BN;

  const int lr = t >> 2;        // 0..63 row within tile
  const int lk = (t & 3) << 2;  // 0,4,8,12

  float acc[4][4] = {};
  const float* Aptr = X + (size_t)(m0 + lr) * 1024 + lk;
  const float* Bptr = Wcat + (size_t)(n0 + lr) * 1024 + lk;

  for (int k0 = 0; k0 < 1024; k0 += BK) {
    float4 av = *(const float4*)(Aptr + k0);
    float4 bv = *(const float4*)(Bptr + k0);
    __syncthreads();
    As[lk + 0][lr] = av.x; As[lk + 1][lr] = av.y;
    As[lk + 2][lr] = av.z; As[lk + 3][lr] = av.w;
    Bs[lk + 0][lr] = bv.x; Bs[lk + 1][lr] = bv.y;
    Bs[lk + 2][lr] = bv.z; Bs[lk + 3][lr] = bv.w;
    __syncthreads();
#pragma unroll
    for (int k = 0; k < BK; ++k) {
      float4 ra = *(const float4*)&As[k][ty << 2];
      float4 rb = *(const float4*)&Bs[k][tx << 2];
      float a[4] = {ra.x, ra.y, ra.z, ra.w};
      float b[4] = {rb.x, rb.y, rb.z, rb.w};
#pragma unroll
      for (int i = 0; i < 4; ++i)
#pragma unroll
        for (int j = 0; j < 4; ++j)
          acc[i][j] = fmaf(a[i], b[j], acc[i][j]);
    }
  }

  const int nbase = n0 + (tx << 2);
  float bj[4];
#pragma unroll
  for (int j = 0; j < 4; ++j) bj[j] = bcat[nbase + j];
  const bool isE = (nbase < 1024);
  const bool isB = (nbase >= 1024) && (nbase < 2048);
#pragma unroll
  for (int i = 0; i < 4; ++i) {
    int m = m0 + (ty << 2) + i;
    float vv[4];
    if (isE) {
#pragma unroll
      for (int j = 0; j < 4; ++j) vv[j] = expf(-expf(acc[i][j] + bj[j]));
    } else if (isB) {
      float4 xv = *(const float4*)(X + (size_t)m * 1024 + (nbase - 1024));
      float xa[4] = {xv.x, xv.y, xv.z, xv.w};
#pragma unroll
      for (int j = 0; j < 4; ++j) vv[j] = (acc[i][j] + bj[j]) * xa[j];
    } else {
#pragma unroll
      for (int j = 0; j < 4; ++j) vv[j] = acc[i][j] + bj[j];
    }
    *(float4*)&Z[(size_t)m * 3072 + nbase] =
        make_float4(vv[0], vv[1], vv[2], vv[3]);
  }
}

// ======================= chunked linear-recurrence scan =======================
#define LSEQ 4096
#define NC 64
#define LC 64  // LSEQ / NC

__global__ __launch_bounds__(256) void scan_chunk(const float* __restrict__ Z,
                                                  float* __restrict__ ac,
                                                  float* __restrict__ uc) {
  int n = blockIdx.x * 256 + threadIdx.x;  // 0..1023
  int c = blockIdx.y;                      // 0..NC-1
  int b = blockIdx.z;                      // 0..3
  const float* base = Z + (size_t)(b * LSEQ + c * LC) * 3072;
  float a = 1.0f, u = 0.0f;
#pragma unroll 4
  for (int l = 0; l < LC; ++l) {
    float e  = base[(size_t)l * 3072 + n];
    float bx = base[(size_t)l * 3072 + 1024 + n];
    a *= e;
    u = fmaf(e, u, bx);
  }
  size_t o = ((size_t)b * NC + c) * 1024 + n;
  ac[o] = a;
  uc[o] = u;
}

__global__ __launch_bounds__(256) void scan_prefix(const float* __restrict__ ac,
                                                   const float* __restrict__ uc,
                                                   float* __restrict__ hin) {
  int idx = blockIdx.x * 256 + threadIdx.x;  // 0..4095
  int b = idx >> 10, n = idx & 1023;
  float h = 0.0f;
  for (int c = 0; c < NC; ++c) {
    size_t o = ((size_t)b * NC + c) * 1024 + n;
    hin[o] = h;
    h = fmaf(ac[o], h, uc[o]);
  }
}

__global__ __launch_bounds__(256) void scan_final(const float* __restrict__ Z,
                                                  const float* __restrict__ hin,
                                                  float* __restrict__ out) {
  int n = blockIdx.x * 256 + threadIdx.x;
  int c = blockIdx.y;
  int b = blockIdx.z;
  const float* base = Z + (size_t)(b * LSEQ + c * LC) * 3072;
  float* obase = out + (size_t)(b * LSEQ + c * LC) * 1024;
  float h = hin[((size_t)b * NC + c) * 1024 + n];
#pragma unroll 4
  for (int l = 0; l < LC; ++l) {
    float e  = base[(size_t)l * 3072 + n];
    float bx = base[(size_t)l * 3072 + 1024 + n];
    float cc = base[(size_t)l * 3072 + 2048 + n];
    h = fmaf(e, h, bx);
    obase[(size_t)l * 1024 + n] = cc * h * 4.0f;
  }
}

// ======================= launch =======================
extern "C" void kernel_launch(void* const* d_in, const int* in_sizes, int n_in,
                              void* d_out, int out_size, void* d_ws, size_t ws_size,
                              hipStream_t stream) {
  const float* x    = (const float*)d_in[0];
  const float* Awmu = (const float*)d_in[1];
  const float* Awlv = (const float*)d_in[2];
  const float* Abmu = (const float*)d_in[3];
  const float* Ablv = (const float*)d_in[4];
  const float* Bwmu = (const float*)d_in[5];
  const float* Bwlv = (const float*)d_in[6];
  const float* Bbmu = (const float*)d_in[7];
  const float* Bblv = (const float*)d_in[8];
  const float* Cwmu = (const float*)d_in[9];
  const float* Cwlv = (const float*)d_in[10];
  const float* Cbmu = (const float*)d_in[11];
  const float* Cblv = (const float*)d_in[12];
  const float* Dwmu = (const float*)d_in[13];
  const float* Dwlv = (const float*)d_in[14];
  const float* Dbmu = (const float*)d_in[15];
  const float* Dblv = (const float*)d_in[16];

  // key(42) -> split(4) -> per-layer split(2): partitionable threefry semantics
  uint32_t k4[4][2];
  for (uint32_t i = 0; i < 4; ++i)
    tf2x32(0u, 42u, 0u, i, k4[i][0], k4[i][1]);  // kA,kB,kC,kdt
  RngKeys kk;
  tf2x32(k4[0][0], k4[0][1], 0u, 0u, kk.wA0, kk.wA1);
  tf2x32(k4[0][0], k4[0][1], 0u, 1u, kk.bA0, kk.bA1);
  tf2x32(k4[1][0], k4[1][1], 0u, 0u, kk.wB0, kk.wB1);
  tf2x32(k4[1][0], k4[1][1], 0u, 1u, kk.bB0, kk.bB1);
  tf2x32(k4[2][0], k4[2][1], 0u, 0u, kk.wC0, kk.wC1);
  tf2x32(k4[2][0], k4[2][1], 0u, 1u, kk.bC0, kk.bC1);
  tf2x32(k4[3][0], k4[3][1], 0u, 0u, kk.wD0, kk.wD1);
  tf2x32(k4[3][0], k4[3][1], 0u, 1u, kk.bD0, kk.bD1);

  // workspace layout
  char* ws = (char*)d_ws;
  const size_t OFF_WCAT = 0;                    // 3*2^20 f32 = 12 MiB
  const size_t OFF_BCAT = 12582912;             // 3072 f32
  const size_t OFF_Z    = 16777216;             // 16384*3072 f32 = 192 MiB
  const size_t OFF_AC   = OFF_Z + (size_t)16384 * 3072 * 4;
  const size_t OFF_UC   = OFF_AC + (size_t)4 * NC * 1024 * 4;
  const size_t OFF_HIN  = OFF_UC + (size_t)4 * NC * 1024 * 4;
  const size_t NEEDED   = OFF_HIN + (size_t)4 * NC * 1024 * 4;
  if (ws_size < NEEDED) return;  // insufficient scratch -> visible as 1872 absmax

  float* Wcat = (float*)(ws + OFF_WCAT);
  float* bcat = (float*)(ws + OFF_BCAT);
  float* Z    = (float*)(ws + OFF_Z);
  float* ac   = (float*)(ws + OFF_AC);
  float* ucv  = (float*)(ws + OFF_UC);
  float* hin  = (float*)(ws + OFF_HIN);
  float* out  = (float*)d_out;

  gen_weights<<<dim3(12288), dim3(256), 0, stream>>>(
      Awmu, Awlv, Dwmu, Dwlv, Bwmu, Bwlv, Cwmu, Cwlv, Wcat, kk);
  gen_bias<<<dim3(12), dim3(256), 0, stream>>>(
      Abmu, Ablv, Dbmu, Dblv, Bbmu, Bblv, Cbmu, Cblv, bcat, kk);
  gemm_fused<<<dim3(3072 / BN, 16384 / BM), dim3(256), 0, stream>>>(
      x, Wcat, bcat, Z);
  scan_chunk<<<dim3(4, NC, 4), dim3(256), 0, stream>>>(Z, ac, ucv);
  scan_prefix<<<dim3(16), dim3(256), 0, stream>>>(ac, ucv, hin);
  scan_final<<<dim3(4, NC, 4), dim3(256), 0, stream>>>(Z, hin, out);
}

// Round 2
// 621.488 us; speedup vs baseline: 2.4750x; 2.4750x over previous
//
#include <hip/hip_runtime.h>
#include <cstdint>

// ======================= threefry-2x32 (JAX-compatible) =======================
__host__ __device__ inline void tf2x32(uint32_t k0, uint32_t k1,
                                       uint32_t x0, uint32_t x1,
                                       uint32_t& o0, uint32_t& o1) {
  uint32_t ks2 = k0 ^ k1 ^ 0x1BD11BDAu;
  uint32_t v0 = x0 + k0, v1 = x1 + k1;
#define TFR(r) { v0 += v1; v1 = (v1 << r) | (v1 >> (32 - r)); v1 ^= v0; }
  TFR(13) TFR(15) TFR(26) TFR(6)
  v0 += k1;  v1 += ks2 + 1u;
  TFR(17) TFR(29) TFR(16) TFR(24)
  v0 += ks2; v1 += k0 + 2u;
  TFR(13) TFR(15) TFR(26) TFR(6)
  v0 += k0;  v1 += k1 + 3u;
  TFR(17) TFR(29) TFR(16) TFR(24)
  v0 += k1;  v1 += ks2 + 4u;
  TFR(13) TFR(15) TFR(26) TFR(6)
  v0 += ks2; v1 += k0 + 5u;
#undef TFR
  o0 = v0; o1 = v1;
}

__device__ inline float erfinv32(float x) {
  float w = -log1pf(-x * x);
  float p;
  if (w < 5.0f) {
    w -= 2.5f;
    p = 2.81022636e-08f;
    p = fmaf(p, w, 3.43273939e-07f);
    p = fmaf(p, w, -3.5233877e-06f);
    p = fmaf(p, w, -4.39150654e-06f);
    p = fmaf(p, w, 0.00021858087f);
    p = fmaf(p, w, -0.00125372503f);
    p = fmaf(p, w, -0.00417768164f);
    p = fmaf(p, w, 0.246640727f);
    p = fmaf(p, w, 1.50140941f);
  } else {
    w = sqrtf(w) - 3.0f;
    p = -0.000200214257f;
    p = fmaf(p, w, 0.000100950558f);
    p = fmaf(p, w, 0.00134934322f);
    p = fmaf(p, w, -0.00367342844f);
    p = fmaf(p, w, 0.00573950773f);
    p = fmaf(p, w, -0.0076224613f);
    p = fmaf(p, w, 0.00943887047f);
    p = fmaf(p, w, 1.00167406f);
    p = fmaf(p, w, 2.83297682f);
  }
  return p * x;
}

__device__ inline float rng_normal(uint32_t k0, uint32_t k1, uint32_t idx) {
  uint32_t o0, o1;
  tf2x32(k0, k1, 0u, idx, o0, o1);
  uint32_t bits = o0 ^ o1;
  float f = __uint_as_float((bits >> 9) | 0x3f800000u) - 1.0f;
  const float lo = -0.999999940395355224609375f;
  float u = fmaxf(lo, f * 2.0f + lo);
  return 1.41421356237f * erfinv32(u);
}

struct RngKeys {
  uint32_t wA0, wA1, bA0, bA1;
  uint32_t wB0, wB1, bB0, bB1;
  uint32_t wC0, wC1, bC0, bC1;
  uint32_t wD0, wD1, bD0, bD1;
};

// ======================= bf16 split helpers =======================
__device__ inline uint16_t f32_to_bf16(float f) {
  uint32_t u = __float_as_uint(f);
  uint32_t r = (u + 0x7FFFu + ((u >> 16) & 1u)) >> 16;
  return (uint16_t)r;
}
__device__ inline float bf16_to_f32(uint16_t h) {
  return __uint_as_float(((uint32_t)h) << 16);
}
__device__ inline void split_bf16(float f, uint16_t& hi, uint16_t& lo) {
  hi = f32_to_bf16(f);
  lo = f32_to_bf16(f - bf16_to_f32(hi));
}

// ======================= weight / bias sampling (write hi/lo bf16) =======================
__global__ __launch_bounds__(256) void gen_weights(
    const float* __restrict__ Awmu, const float* __restrict__ Awlv,
    const float* __restrict__ Dwmu, const float* __restrict__ Dwlv,
    const float* __restrict__ Bwmu, const float* __restrict__ Bwlv,
    const float* __restrict__ Cwmu, const float* __restrict__ Cwlv,
    uint16_t* __restrict__ Wh, uint16_t* __restrict__ Wl, RngKeys kk) {
  uint32_t idx = blockIdx.x * 256u + threadIdx.x;  // [0, 3*2^20)
  uint32_t sel = idx >> 20;
  uint32_t e = idx & 0xFFFFFu;
  float w;
  if (sel == 0u) {
    w = Awmu[e] + expf(0.5f * Awlv[e]) * rng_normal(kk.wA0, kk.wA1, e)
      + Dwmu[e] + expf(0.5f * Dwlv[e]) * rng_normal(kk.wD0, kk.wD1, e);
  } else if (sel == 1u) {
    w = Bwmu[e] + expf(0.5f * Bwlv[e]) * rng_normal(kk.wB0, kk.wB1, e);
  } else {
    w = Cwmu[e] + expf(0.5f * Cwlv[e]) * rng_normal(kk.wC0, kk.wC1, e);
  }
  uint16_t hi, lo;
  split_bf16(w, hi, lo);
  Wh[idx] = hi;
  Wl[idx] = lo;
}

__global__ __launch_bounds__(256) void gen_bias(
    const float* __restrict__ Abmu, const float* __restrict__ Ablv,
    const float* __restrict__ Dbmu, const float* __restrict__ Dblv,
    const float* __restrict__ Bbmu, const float* __restrict__ Bblv,
    const float* __restrict__ Cbmu, const float* __restrict__ Cblv,
    float* __restrict__ bcat, RngKeys kk) {
  uint32_t o = blockIdx.x * 256u + threadIdx.x;  // 0..3071
  uint32_t e = o & 1023u;
  float b;
  if (o < 1024u)
    b = Abmu[e] + expf(0.5f * Ablv[e]) * rng_normal(kk.bA0, kk.bA1, e)
      + Dbmu[e] + expf(0.5f * Dblv[e]) * rng_normal(kk.bD0, kk.bD1, e);
  else if (o < 2048u)
    b = Bbmu[e] + expf(0.5f * Bblv[e]) * rng_normal(kk.bB0, kk.bB1, e);
  else
    b = Cbmu[e] + expf(0.5f * Cblv[e]) * rng_normal(kk.bC0, kk.bC1, e);
  bcat[o] = b;
}

// ======================= x -> hi/lo bf16 =======================
__global__ __launch_bounds__(256) void convert_x(const float* __restrict__ X,
                                                 uint16_t* __restrict__ Xh,
                                                 uint16_t* __restrict__ Xl) {
  size_t i4 = ((size_t)blockIdx.x * 256 + threadIdx.x) * 4;
  float4 v = *(const float4*)(X + i4);
  ushort4 h, l;
  split_bf16(v.x, h.x, l.x);
  split_bf16(v.y, h.y, l.y);
  split_bf16(v.z, h.z, l.z);
  split_bf16(v.w, h.w, l.w);
  *(ushort4*)(Xh + i4) = h;
  *(ushort4*)(Xl + i4) = l;
}

// ======================= split-bf16 MFMA GEMM + fused epilogue =======================
// C[M=16384, N=3072] = X[M,K=1024] * W[N,K]^T, via hi/lo bf16 split (3 MFMA).
// seg 0 (n<1024):        Z[m*2048 + n]        = exp(-exp(v + bias))       (E)
// seg 1 (1024<=n<2048):  Z[m*2048 + n]        = (v + bias) * x[m][n-1024] (Bx)
// seg 2 (n>=2048):       out[m*1024 + n-2048] = v + bias                  (C)
typedef __attribute__((ext_vector_type(8))) short bf16x8;
typedef __attribute__((ext_vector_type(4))) float f32x4;

__device__ inline void gl2lds16(const void* g, void* l) {
  __builtin_amdgcn_global_load_lds(
      (const __attribute__((address_space(1))) void*)g,
      (__attribute__((address_space(3))) void*)l, 16, 0, 0);
}

__global__ __launch_bounds__(256) void gemm_fused(
    const uint16_t* __restrict__ Xh, const uint16_t* __restrict__ Xl,
    const uint16_t* __restrict__ Wh, const uint16_t* __restrict__ Wl,
    const float* __restrict__ X, const float* __restrict__ bcat,
    float* __restrict__ Z, float* __restrict__ out) {
  __shared__ uint16_t sAh[128 * 32];
  __shared__ uint16_t sAl[128 * 32];
  __shared__ uint16_t sBh[128 * 32];
  __shared__ uint16_t sBl[128 * 32];

  const int tid = threadIdx.x;
  const int m0 = blockIdx.y * 128;
  const int n0 = blockIdx.x * 128;

  // staging map: row = tid>>2 (+64 for 2nd group), k-elem off = (tid&3)*8
  const int srow = tid >> 2;
  const int soff = (tid & 3) * 8;
  const uint16_t* gAh = Xh + (size_t)(m0 + srow) * 1024 + soff;
  const uint16_t* gAl = Xl + (size_t)(m0 + srow) * 1024 + soff;
  const uint16_t* gBh = Wh + (size_t)(n0 + srow) * 1024 + soff;
  const uint16_t* gBl = Wl + (size_t)(n0 + srow) * 1024 + soff;
  char* lAh = (char*)sAh + tid * 16;
  char* lAl = (char*)sAl + tid * 16;
  char* lBh = (char*)sBh + tid * 16;
  char* lBl = (char*)sBl + tid * 16;

  const int lane = tid & 63;
  const int wave = tid >> 6;
  const int wm = wave >> 1, wn = wave & 1;
  const int fr = lane & 15;  // m/n within a 16-tile
  const int q = lane >> 4;   // k-group (8 elems each)

  f32x4 acc[4][4] = {};

  for (int k0 = 0; k0 < 1024; k0 += 32) {
    __syncthreads();  // previous iter's ds_reads done before overwrite
    gl2lds16(gAh + k0, lAh);
    gl2lds16(gAh + 64 * 1024 + k0, lAh + 4096);
    gl2lds16(gAl + k0, lAl);
    gl2lds16(gAl + 64 * 1024 + k0, lAl + 4096);
    gl2lds16(gBh + k0, lBh);
    gl2lds16(gBh + 64 * 1024 + k0, lBh + 4096);
    gl2lds16(gBl + k0, lBl);
    gl2lds16(gBl + 64 * 1024 + k0, lBl + 4096);
    __syncthreads();  // compiler drains vmcnt before barrier

    bf16x8 ah[4], al[4], bh[4], bl[4];
#pragma unroll
    for (int t = 0; t < 4; ++t) {
      int ar = (wm * 64 + t * 16 + fr) * 32 + q * 8;
      int br = (wn * 64 + t * 16 + fr) * 32 + q * 8;
      ah[t] = *(const bf16x8*)&sAh[ar];
      al[t] = *(const bf16x8*)&sAl[ar];
      bh[t] = *(const bf16x8*)&sBh[br];
      bl[t] = *(const bf16x8*)&sBl[br];
    }
#pragma unroll
    for (int mt = 0; mt < 4; ++mt)
#pragma unroll
      for (int nt = 0; nt < 4; ++nt) {
        acc[mt][nt] = __builtin_amdgcn_mfma_f32_16x16x32_bf16(
            ah[mt], bh[nt], acc[mt][nt], 0, 0, 0);
        acc[mt][nt] = __builtin_amdgcn_mfma_f32_16x16x32_bf16(
            ah[mt], bl[nt], acc[mt][nt], 0, 0, 0);
        acc[mt][nt] = __builtin_amdgcn_mfma_f32_16x16x32_bf16(
            al[mt], bh[nt], acc[mt][nt], 0, 0, 0);
      }
  }

  // epilogue: C/D layout col(n)=lane&15, row(m)=(lane>>4)*4+reg
  const int seg = n0 >> 10;  // block-uniform
  const int mrow = (lane >> 4) * 4;
#pragma unroll
  for (int nt = 0; nt < 4; ++nt) {
    int n = n0 + wn * 64 + nt * 16 + fr;
    float bv = bcat[n];
#pragma unroll
    for (int mt = 0; mt < 4; ++mt) {
      int mbase = m0 + wm * 64 + mt * 16 + mrow;
      f32x4 a = acc[mt][nt];
#pragma unroll
      for (int r = 0; r < 4; ++r) {
        int m = mbase + r;
        float v = a[r] + bv;
        if (seg == 0) {
          Z[(size_t)m * 2048 + n] = expf(-expf(v));
        } else if (seg == 1) {
          Z[(size_t)m * 2048 + n] = v * X[(size_t)m * 1024 + (n - 1024)];
        } else {
          out[(size_t)m * 1024 + (n - 2048)] = v;
        }
      }
    }
  }
}

// ======================= chunked linear-recurrence scan =======================
#define LSEQ 4096
#define NC 64
#define LC 64
#define ZW 2048

__global__ __launch_bounds__(256) void scan_chunk(const float* __restrict__ Z,
                                                  float* __restrict__ ac,
                                                  float* __restrict__ uc) {
  int n = blockIdx.x * 256 + threadIdx.x;
  int c = blockIdx.y;
  int b = blockIdx.z;
  const float* base = Z + (size_t)(b * LSEQ + c * LC) * ZW;
  float a = 1.0f, u = 0.0f;
#pragma unroll 4
  for (int l = 0; l < LC; ++l) {
    float e  = base[(size_t)l * ZW + n];
    float bx = base[(size_t)l * ZW + 1024 + n];
    a *= e;
    u = fmaf(e, u, bx);
  }
  size_t o = ((size_t)b * NC + c) * 1024 + n;
  ac[o] = a;
  uc[o] = u;
}

__global__ __launch_bounds__(256) void scan_prefix(const float* __restrict__ ac,
                                                   const float* __restrict__ uc,
                                                   float* __restrict__ hin) {
  int idx = blockIdx.x * 256 + threadIdx.x;  // 0..4095
  int b = idx >> 10, n = idx & 1023;
  float h = 0.0f;
  for (int c = 0; c < NC; ++c) {
    size_t o = ((size_t)b * NC + c) * 1024 + n;
    hin[o] = h;
    h = fmaf(ac[o], h, uc[o]);
  }
}

__global__ __launch_bounds__(256) void scan_final(const float* __restrict__ Z,
                                                  const float* __restrict__ hin,
                                                  float* __restrict__ out) {
  int n = blockIdx.x * 256 + threadIdx.x;
  int c = blockIdx.y;
  int b = blockIdx.z;
  const float* base = Z + (size_t)(b * LSEQ + c * LC) * ZW;
  float* obase = out + (size_t)(b * LSEQ + c * LC) * 1024;
  float h = hin[((size_t)b * NC + c) * 1024 + n];
#pragma unroll 4
  for (int l = 0; l < LC; ++l) {
    float e  = base[(size_t)l * ZW + n];
    float bx = base[(size_t)l * ZW + 1024 + n];
    float cc = obase[(size_t)l * 1024 + n];  // C written by gemm epilogue
    h = fmaf(e, h, bx);
    obase[(size_t)l * 1024 + n] = cc * h * 4.0f;
  }
}

// ======================= launch =======================
extern "C" void kernel_launch(void* const* d_in, const int* in_sizes, int n_in,
                              void* d_out, int out_size, void* d_ws, size_t ws_size,
                              hipStream_t stream) {
  const float* x    = (const float*)d_in[0];
  const float* Awmu = (const float*)d_in[1];
  const float* Awlv = (const float*)d_in[2];
  const float* Abmu = (const float*)d_in[3];
  const float* Ablv = (const float*)d_in[4];
  const float* Bwmu = (const float*)d_in[5];
  const float* Bwlv = (const float*)d_in[6];
  const float* Bbmu = (const float*)d_in[7];
  const float* Bblv = (const float*)d_in[8];
  const float* Cwmu = (const float*)d_in[9];
  const float* Cwlv = (const float*)d_in[10];
  const float* Cbmu = (const float*)d_in[11];
  const float* Cblv = (const float*)d_in[12];
  const float* Dwmu = (const float*)d_in[13];
  const float* Dwlv = (const float*)d_in[14];
  const float* Dbmu = (const float*)d_in[15];
  const float* Dblv = (const float*)d_in[16];

  uint32_t k4[4][2];
  for (uint32_t i = 0; i < 4; ++i)
    tf2x32(0u, 42u, 0u, i, k4[i][0], k4[i][1]);  // kA,kB,kC,kdt
  RngKeys kk;
  tf2x32(k4[0][0], k4[0][1], 0u, 0u, kk.wA0, kk.wA1);
  tf2x32(k4[0][0], k4[0][1], 0u, 1u, kk.bA0, kk.bA1);
  tf2x32(k4[1][0], k4[1][1], 0u, 0u, kk.wB0, kk.wB1);
  tf2x32(k4[1][0], k4[1][1], 0u, 1u, kk.bB0, kk.bB1);
  tf2x32(k4[2][0], k4[2][1], 0u, 0u, kk.wC0, kk.wC1);
  tf2x32(k4[2][0], k4[2][1], 0u, 1u, kk.bC0, kk.bC1);
  tf2x32(k4[3][0], k4[3][1], 0u, 0u, kk.wD0, kk.wD1);
  tf2x32(k4[3][0], k4[3][1], 0u, 1u, kk.bD0, kk.bD1);

  // workspace layout (211 MiB total, same as passing round-1 budget)
  char* ws = (char*)d_ws;
  const size_t OFF_WH   = 0;                         // 3072*1024*2 = 6 MiB
  const size_t OFF_WL   = 6291456;                   // 6 MiB
  const size_t OFF_BCAT = 12582912;                  // 3072 f32
  const size_t OFF_XH   = 16777216;                  // 16384*1024*2 = 32 MiB
  const size_t OFF_XL   = 50331648;                  // 32 MiB
  const size_t OFF_Z    = 83886080;                  // 16384*2048*4 = 128 MiB
  const size_t OFF_AC   = OFF_Z + (size_t)16384 * 2048 * 4;
  const size_t OFF_UC   = OFF_AC + (size_t)4 * NC * 1024 * 4;
  const size_t OFF_HIN  = OFF_UC + (size_t)4 * NC * 1024 * 4;
  const size_t NEEDED   = OFF_HIN + (size_t)4 * NC * 1024 * 4;
  if (ws_size < NEEDED) return;

  uint16_t* Wh  = (uint16_t*)(ws + OFF_WH);
  uint16_t* Wl  = (uint16_t*)(ws + OFF_WL);
  float*    bcat= (float*)(ws + OFF_BCAT);
  uint16_t* Xh  = (uint16_t*)(ws + OFF_XH);
  uint16_t* Xl  = (uint16_t*)(ws + OFF_XL);
  float*    Z   = (float*)(ws + OFF_Z);
  float*    ac  = (float*)(ws + OFF_AC);
  float*    ucv = (float*)(ws + OFF_UC);
  float*    hin = (float*)(ws + OFF_HIN);
  float*    out = (float*)d_out;

  gen_weights<<<dim3(12288), dim3(256), 0, stream>>>(
      Awmu, Awlv, Dwmu, Dwlv, Bwmu, Bwlv, Cwmu, Cwlv, Wh, Wl, kk);
  gen_bias<<<dim3(12), dim3(256), 0, stream>>>(
      Abmu, Ablv, Dbmu, Dblv, Bbmu, Bblv, Cbmu, Cblv, bcat, kk);
  convert_x<<<dim3(16384), dim3(256), 0, stream>>>(x, Xh, Xl);
  gemm_fused<<<dim3(24, 128), dim3(256), 0, stream>>>(
      Xh, Xl, Wh, Wl, x, bcat, Z, out);
  scan_chunk<<<dim3(4, NC, 4), dim3(256), 0, stream>>>(Z, ac, ucv);
  scan_prefix<<<dim3(16), dim3(256), 0, stream>>>(ac, ucv, hin);
  scan_final<<<dim3(4, NC, 4), dim3(256), 0, stream>>>(Z, hin, out);
}

// Round 3
// 386.642 us; speedup vs baseline: 3.9784x; 1.6074x over previous
//
#include <hip/hip_runtime.h>
#include <cstdint>

// ======================= threefry-2x32 (JAX-compatible) =======================
__host__ __device__ inline void tf2x32(uint32_t k0, uint32_t k1,
                                       uint32_t x0, uint32_t x1,
                                       uint32_t& o0, uint32_t& o1) {
  uint32_t ks2 = k0 ^ k1 ^ 0x1BD11BDAu;
  uint32_t v0 = x0 + k0, v1 = x1 + k1;
#define TFR(r) { v0 += v1; v1 = (v1 << r) | (v1 >> (32 - r)); v1 ^= v0; }
  TFR(13) TFR(15) TFR(26) TFR(6)
  v0 += k1;  v1 += ks2 + 1u;
  TFR(17) TFR(29) TFR(16) TFR(24)
  v0 += ks2; v1 += k0 + 2u;
  TFR(13) TFR(15) TFR(26) TFR(6)
  v0 += k0;  v1 += k1 + 3u;
  TFR(17) TFR(29) TFR(16) TFR(24)
  v0 += k1;  v1 += ks2 + 4u;
  TFR(13) TFR(15) TFR(26) TFR(6)
  v0 += ks2; v1 += k0 + 5u;
#undef TFR
  o0 = v0; o1 = v1;
}

__device__ inline float erfinv32(float x) {
  float w = -log1pf(-x * x);
  float p;
  if (w < 5.0f) {
    w -= 2.5f;
    p = 2.81022636e-08f;
    p = fmaf(p, w, 3.43273939e-07f);
    p = fmaf(p, w, -3.5233877e-06f);
    p = fmaf(p, w, -4.39150654e-06f);
    p = fmaf(p, w, 0.00021858087f);
    p = fmaf(p, w, -0.00125372503f);
    p = fmaf(p, w, -0.00417768164f);
    p = fmaf(p, w, 0.246640727f);
    p = fmaf(p, w, 1.50140941f);
  } else {
    w = sqrtf(w) - 3.0f;
    p = -0.000200214257f;
    p = fmaf(p, w, 0.000100950558f);
    p = fmaf(p, w, 0.00134934322f);
    p = fmaf(p, w, -0.00367342844f);
    p = fmaf(p, w, 0.00573950773f);
    p = fmaf(p, w, -0.0076224613f);
    p = fmaf(p, w, 0.00943887047f);
    p = fmaf(p, w, 1.00167406f);
    p = fmaf(p, w, 2.83297682f);
  }
  return p * x;
}

__device__ inline float rng_normal(uint32_t k0, uint32_t k1, uint32_t idx) {
  uint32_t o0, o1;
  tf2x32(k0, k1, 0u, idx, o0, o1);
  uint32_t bits = o0 ^ o1;
  float f = __uint_as_float((bits >> 9) | 0x3f800000u) - 1.0f;
  const float lo = -0.999999940395355224609375f;
  float u = fmaxf(lo, f * 2.0f + lo);
  return 1.41421356237f * erfinv32(u);
}

struct RngKeys {
  uint32_t wA0, wA1, bA0, bA1;
  uint32_t wB0, wB1, bB0, bB1;
  uint32_t wC0, wC1, bC0, bC1;
  uint32_t wD0, wD1, bD0, bD1;
};

typedef _Float16 f16x8 __attribute__((ext_vector_type(8)));
typedef _Float16 f16x4 __attribute__((ext_vector_type(4)));
typedef float f32x4 __attribute__((ext_vector_type(4)));

// ======================= weight / bias sampling (f16 weights) =======================
__global__ __launch_bounds__(256) void gen_weights(
    const float* __restrict__ Awmu, const float* __restrict__ Awlv,
    const float* __restrict__ Dwmu, const float* __restrict__ Dwlv,
    const float* __restrict__ Bwmu, const float* __restrict__ Bwlv,
    const float* __restrict__ Cwmu, const float* __restrict__ Cwlv,
    _Float16* __restrict__ Wh, RngKeys kk) {
  uint32_t idx = blockIdx.x * 256u + threadIdx.x;  // [0, 3*2^20)
  uint32_t sel = idx >> 20;
  uint32_t e = idx & 0xFFFFFu;
  float w;
  if (sel == 0u) {
    w = Awmu[e] + expf(0.5f * Awlv[e]) * rng_normal(kk.wA0, kk.wA1, e)
      + Dwmu[e] + expf(0.5f * Dwlv[e]) * rng_normal(kk.wD0, kk.wD1, e);
  } else if (sel == 1u) {
    w = Bwmu[e] + expf(0.5f * Bwlv[e]) * rng_normal(kk.wB0, kk.wB1, e);
  } else {
    w = Cwmu[e] + expf(0.5f * Cwlv[e]) * rng_normal(kk.wC0, kk.wC1, e);
  }
  Wh[idx] = (_Float16)w;
}

__global__ __launch_bounds__(256) void gen_bias(
    const float* __restrict__ Abmu, const float* __restrict__ Ablv,
    const float* __restrict__ Dbmu, const float* __restrict__ Dblv,
    const float* __restrict__ Bbmu, const float* __restrict__ Bblv,
    const float* __restrict__ Cbmu, const float* __restrict__ Cblv,
    float* __restrict__ bcat, RngKeys kk) {
  uint32_t o = blockIdx.x * 256u + threadIdx.x;  // 0..3071
  uint32_t e = o & 1023u;
  float b;
  if (o < 1024u)
    b = Abmu[e] + expf(0.5f * Ablv[e]) * rng_normal(kk.bA0, kk.bA1, e)
      + Dbmu[e] + expf(0.5f * Dblv[e]) * rng_normal(kk.bD0, kk.bD1, e);
  else if (o < 2048u)
    b = Bbmu[e] + expf(0.5f * Bblv[e]) * rng_normal(kk.bB0, kk.bB1, e);
  else
    b = Cbmu[e] + expf(0.5f * Cblv[e]) * rng_normal(kk.bC0, kk.bC1, e);
  bcat[o] = b;
}

// ======================= x -> f16 =======================
__global__ __launch_bounds__(256) void convert_x(const float* __restrict__ X,
                                                 _Float16* __restrict__ Xh) {
  size_t i4 = ((size_t)blockIdx.x * 256 + threadIdx.x) * 4;
  float4 v = *(const float4*)(X + i4);
  f16x4 h;
  h[0] = (_Float16)v.x; h[1] = (_Float16)v.y;
  h[2] = (_Float16)v.z; h[3] = (_Float16)v.w;
  *(f16x4*)(Xh + i4) = h;
}

// ======================= f16 MFMA GEMM + fused epilogue =======================
// C[M=16384, N=3072] = X[M,K=1024] * W[N,K]^T, single-pass f16 MFMA.
// seg 0 (n<1024):        Z[m*2048 + n]        = f16(exp(-exp(v + bias)))   (E)
// seg 1 (1024<=n<2048):  Z[m*2048 + n]        = f16((v+bias) * x[m][n-1024]) (Bx)
// seg 2 (n>=2048):       out[m*1024 + n-2048] = v + bias  (f32)            (C)
__device__ inline void gl2lds16(const void* g, void* l) {
  __builtin_amdgcn_global_load_lds(
      (const __attribute__((address_space(1))) void*)g,
      (__attribute__((address_space(3))) void*)l, 16, 0, 0);
}

__global__ __launch_bounds__(256, 4) void gemm_fused(
    const _Float16* __restrict__ Xh, const _Float16* __restrict__ Wh,
    const float* __restrict__ X, const float* __restrict__ bcat,
    _Float16* __restrict__ Z, float* __restrict__ out) {
  __shared__ _Float16 sA[128 * 32];  // 8 KB, swizzled chunk layout
  __shared__ _Float16 sB[128 * 32];  // 8 KB

  const int tid = threadIdx.x;
  const int m0 = blockIdx.y * 128;
  const int n0 = blockIdx.x * 128;

  // staging: thread t stages global (row=t>>2, chunk cg) into LDS slot t*16B.
  // swizzle: cg = (t&3) ^ ((row>>1)&3) so reads spread over 8 bank positions.
  const int srow = tid >> 2;
  const int scg = (tid & 3) ^ ((srow >> 1) & 3);
  const _Float16* gA = Xh + (size_t)(m0 + srow) * 1024 + scg * 8;
  const _Float16* gB = Wh + (size_t)(n0 + srow) * 1024 + scg * 8;
  char* lA = (char*)sA + tid * 16;
  char* lB = (char*)sB + tid * 16;

  const int lane = tid & 63;
  const int wave = tid >> 6;
  const int wm = wave >> 1, wn = wave & 1;
  const int fr = lane & 15;  // m/n within a 16-tile
  const int q = lane >> 4;   // k-chunk (8 f16 each)
  const int kc = q ^ ((fr >> 1) & 3);  // swizzled k-chunk (lane-constant)

  f32x4 acc[4][4] = {};

  for (int k0 = 0; k0 < 1024; k0 += 32) {
    __syncthreads();  // previous iter's ds_reads done before overwrite
    gl2lds16(gA + k0, lA);
    gl2lds16(gA + 64 * 1024 + k0, lA + 4096);
    gl2lds16(gB + k0, lB);
    gl2lds16(gB + 64 * 1024 + k0, lB + 4096);
    __syncthreads();  // compiler drains vmcnt before barrier

    f16x8 ah[4], bh[4];
#pragma unroll
    for (int t = 0; t < 4; ++t) {
      int ar = (wm * 64 + t * 16 + fr) * 32 + kc * 8;
      int br = (wn * 64 + t * 16 + fr) * 32 + kc * 8;
      ah[t] = *(const f16x8*)&sA[ar];
      bh[t] = *(const f16x8*)&sB[br];
    }
#pragma unroll
    for (int mt = 0; mt < 4; ++mt)
#pragma unroll
      for (int nt = 0; nt < 4; ++nt)
        acc[mt][nt] = __builtin_amdgcn_mfma_f32_16x16x32_f16(
            ah[mt], bh[nt], acc[mt][nt], 0, 0, 0);
  }

  // epilogue: C/D layout col(n)=lane&15, row(m)=(lane>>4)*4+reg
  const int seg = n0 >> 10;  // block-uniform
  const int mrow = (lane >> 4) * 4;
#pragma unroll
  for (int nt = 0; nt < 4; ++nt) {
    int n = n0 + wn * 64 + nt * 16 + fr;
    float bv = bcat[n];
#pragma unroll
    for (int mt = 0; mt < 4; ++mt) {
      int mbase = m0 + wm * 64 + mt * 16 + mrow;
      f32x4 a = acc[mt][nt];
#pragma unroll
      for (int r = 0; r < 4; ++r) {
        int m = mbase + r;
        float v = a[r] + bv;
        if (seg == 0) {
          Z[(size_t)m * 2048 + n] = (_Float16)expf(-expf(v));
        } else if (seg == 1) {
          Z[(size_t)m * 2048 + n] =
              (_Float16)(v * X[(size_t)m * 1024 + (n - 1024)]);
        } else {
          out[(size_t)m * 1024 + (n - 2048)] = v;
        }
      }
    }
  }
}

// ======================= chunked linear-recurrence scan =======================
#define LSEQ 4096
#define NC 64
#define LC 64
#define ZW 2048

__global__ __launch_bounds__(256) void scan_chunk(const _Float16* __restrict__ Z,
                                                  float* __restrict__ ac,
                                                  float* __restrict__ uc) {
  int n = blockIdx.x * 256 + threadIdx.x;
  int c = blockIdx.y;
  int b = blockIdx.z;
  const _Float16* base = Z + (size_t)(b * LSEQ + c * LC) * ZW;
  float a = 1.0f, u = 0.0f;
#pragma unroll 4
  for (int l = 0; l < LC; ++l) {
    float e  = (float)base[(size_t)l * ZW + n];
    float bx = (float)base[(size_t)l * ZW + 1024 + n];
    a *= e;
    u = fmaf(e, u, bx);
  }
  size_t o = ((size_t)b * NC + c) * 1024 + n;
  ac[o] = a;
  uc[o] = u;
}

__global__ __launch_bounds__(256) void scan_prefix(const float* __restrict__ ac,
                                                   const float* __restrict__ uc,
                                                   float* __restrict__ hin) {
  int idx = blockIdx.x * 256 + threadIdx.x;  // 0..4095
  int b = idx >> 10, n = idx & 1023;
  float h = 0.0f;
  for (int c = 0; c < NC; ++c) {
    size_t o = ((size_t)b * NC + c) * 1024 + n;
    hin[o] = h;
    h = fmaf(ac[o], h, uc[o]);
  }
}

__global__ __launch_bounds__(256) void scan_final(const _Float16* __restrict__ Z,
                                                  const float* __restrict__ hin,
                                                  float* __restrict__ out) {
  int n = blockIdx.x * 256 + threadIdx.x;
  int c = blockIdx.y;
  int b = blockIdx.z;
  const _Float16* base = Z + (size_t)(b * LSEQ + c * LC) * ZW;
  float* obase = out + (size_t)(b * LSEQ + c * LC) * 1024;
  float h = hin[((size_t)b * NC + c) * 1024 + n];
#pragma unroll 4
  for (int l = 0; l < LC; ++l) {
    float e  = (float)base[(size_t)l * ZW + n];
    float bx = (float)base[(size_t)l * ZW + 1024 + n];
    float cc = obase[(size_t)l * 1024 + n];  // C written by gemm epilogue (f32)
    h = fmaf(e, h, bx);
    obase[(size_t)l * 1024 + n] = cc * h * 4.0f;
  }
}

// ======================= launch =======================
extern "C" void kernel_launch(void* const* d_in, const int* in_sizes, int n_in,
                              void* d_out, int out_size, void* d_ws, size_t ws_size,
                              hipStream_t stream) {
  const float* x    = (const float*)d_in[0];
  const float* Awmu = (const float*)d_in[1];
  const float* Awlv = (const float*)d_in[2];
  const float* Abmu = (const float*)d_in[3];
  const float* Ablv = (const float*)d_in[4];
  const float* Bwmu = (const float*)d_in[5];
  const float* Bwlv = (const float*)d_in[6];
  const float* Bbmu = (const float*)d_in[7];
  const float* Bblv = (const float*)d_in[8];
  const float* Cwmu = (const float*)d_in[9];
  const float* Cwlv = (const float*)d_in[10];
  const float* Cbmu = (const float*)d_in[11];
  const float* Cblv = (const float*)d_in[12];
  const float* Dwmu = (const float*)d_in[13];
  const float* Dwlv = (const float*)d_in[14];
  const float* Dbmu = (const float*)d_in[15];
  const float* Dblv = (const float*)d_in[16];

  uint32_t k4[4][2];
  for (uint32_t i = 0; i < 4; ++i)
    tf2x32(0u, 42u, 0u, i, k4[i][0], k4[i][1]);  // kA,kB,kC,kdt
  RngKeys kk;
  tf2x32(k4[0][0], k4[0][1], 0u, 0u, kk.wA0, kk.wA1);
  tf2x32(k4[0][0], k4[0][1], 0u, 1u, kk.bA0, kk.bA1);
  tf2x32(k4[1][0], k4[1][1], 0u, 0u, kk.wB0, kk.wB1);
  tf2x32(k4[1][0], k4[1][1], 0u, 1u, kk.bB0, kk.bB1);
  tf2x32(k4[2][0], k4[2][1], 0u, 0u, kk.wC0, kk.wC1);
  tf2x32(k4[2][0], k4[2][1], 0u, 1u, kk.bC0, kk.bC1);
  tf2x32(k4[3][0], k4[3][1], 0u, 0u, kk.wD0, kk.wD1);
  tf2x32(k4[3][0], k4[3][1], 0u, 1u, kk.bD0, kk.bD1);

  // workspace layout (~112 MiB)
  char* ws = (char*)d_ws;
  const size_t OFF_WH   = 0;                    // 3072*1024*2 = 6 MiB
  const size_t OFF_BCAT = 6291456;              // 3072 f32
  const size_t OFF_XH   = 8388608;              // 16384*1024*2 = 32 MiB
  const size_t OFF_Z    = 41943040;             // 16384*2048*2 = 64 MiB
  const size_t OFF_AC   = OFF_Z + (size_t)16384 * 2048 * 2;
  const size_t OFF_UC   = OFF_AC + (size_t)4 * NC * 1024 * 4;
  const size_t OFF_HIN  = OFF_UC + (size_t)4 * NC * 1024 * 4;
  const size_t NEEDED   = OFF_HIN + (size_t)4 * NC * 1024 * 4;
  if (ws_size < NEEDED) return;

  _Float16* Wh  = (_Float16*)(ws + OFF_WH);
  float*    bcat= (float*)(ws + OFF_BCAT);
  _Float16* Xh  = (_Float16*)(ws + OFF_XH);
  _Float16* Z   = (_Float16*)(ws + OFF_Z);
  float*    ac  = (float*)(ws + OFF_AC);
  float*    ucv = (float*)(ws + OFF_UC);
  float*    hin = (float*)(ws + OFF_HIN);
  float*    out = (float*)d_out;

  gen_weights<<<dim3(12288), dim3(256), 0, stream>>>(
      Awmu, Awlv, Dwmu, Dwlv, Bwmu, Bwlv, Cwmu, Cwlv, Wh, kk);
  gen_bias<<<dim3(12), dim3(256), 0, stream>>>(
      Abmu, Ablv, Dbmu, Dblv, Bbmu, Bblv, Cbmu, Cblv, bcat, kk);
  convert_x<<<dim3(16384), dim3(256), 0, stream>>>(x, Xh);
  gemm_fused<<<dim3(24, 128), dim3(256), 0, stream>>>(
      Xh, Wh, x, bcat, Z, out);
  scan_chunk<<<dim3(4, NC, 4), dim3(256), 0, stream>>>(Z, ac, ucv);
  scan_prefix<<<dim3(16), dim3(256), 0, stream>>>(ac, ucv, hin);
  scan_final<<<dim3(4, NC, 4), dim3(256), 0, stream>>>(Z, hin, out);
}